// Round 13
// baseline (34.004 us; speedup 1.0000x reference)
//
#include <hip/hip_runtime.h>

// FK over the SMPL joint tree — counted-vmcnt double-buffer pipeline AT
// full occupancy (the R11 x R12 combination).
//
// Tile = 14 frames = 7392 B; double-buffered LDS = 14784 B -> 11 blocks/CU
// (same residency as R11) with cross-tile prefetch (same pipeline as R12).
// 2816 persistent single-wave blocks grid-stride over 7168 tiles (~2.5 ea).
// Per iteration (8 loads + 8 stores VM ops):
//   s_waitcnt vmcnt(8)   -> tile t's 8 DMAs done (8 newer ops = t-1's
//                           stores stay in flight; never drain to 0)
//   stage(t+G) -> buf^1  -> next tile's loads outstanding through compute
//   compute(t)           -> half-split: lanes fi<14 of each half own one
//                           frame; joints 0-10 / 11-21; Rg8/Rg9 handoff
//                           via __shfl_xor(.,32)
//   store(t)             -> 8 coalesced float4 stores (fire-and-forget)
// NO __syncthreads in the loop (would drain vmcnt(0) and kill the pipe).

#define TPB 64
#define TILE_FRAMES 14
#define TILE_FLOATS (TILE_FRAMES * 132)  // 1848 floats = 7392 B

__device__ __forceinline__ void local_rot(const float* s, float* L) {
    float a1x = s[0], a1y = s[1], a1z = s[2];
    float a2x = s[3], a2y = s[4], a2z = s[5];
    float n1 = sqrtf(a1x * a1x + a1y * a1y + a1z * a1z);
    float i1 = 1.0f / fmaxf(n1, 1e-12f);
    float b1x = a1x * i1, b1y = a1y * i1, b1z = a1z * i1;
    float dt = b1x * a2x + b1y * a2y + b1z * a2z;
    float cx = a2x - dt * b1x, cy = a2y - dt * b1y, cz = a2z - dt * b1z;
    float n2 = sqrtf(cx * cx + cy * cy + cz * cz);
    float i2 = 1.0f / fmaxf(n2, 1e-12f);
    L[0] = b1x; L[1] = b1y; L[2] = b1z;
    L[3] = cx * i2; L[4] = cy * i2; L[5] = cz * i2;
    L[6] = L[1] * L[5] - L[2] * L[4];
    L[7] = L[2] * L[3] - L[0] * L[5];
    L[8] = L[0] * L[4] - L[1] * L[3];
}

__device__ __forceinline__ void matmul3(float* G, const float* P, const float* L) {
#pragma unroll
    for (int r = 0; r < 3; ++r)
#pragma unroll
        for (int c = 0; c < 3; ++c)
            G[3 * r + c] = P[3 * r + 0] * L[0 + c] +
                           P[3 * r + 1] * L[3 + c] +
                           P[3 * r + 2] * L[6 + c];
}

// 8 DMA instructions: 7 full 1024B chunks + 224B tail (lanes 0-13).
__device__ __forceinline__ void stage_tile(const float* __restrict__ in,
                                           int tile, float* buf, int lane) {
    const float* gin = in + (size_t)tile * TILE_FLOATS;
#pragma unroll
    for (int k = 0; k < 7; ++k)
        __builtin_amdgcn_global_load_lds(
            (const __attribute__((address_space(1))) void*)(gin + k * 256 + lane * 4),
            (__attribute__((address_space(3))) void*)(buf + k * 256), 16, 0, 0);
    if (lane < TILE_FRAMES)
        __builtin_amdgcn_global_load_lds(
            (const __attribute__((address_space(1))) void*)(gin + 1792 + lane * 4),
            (__attribute__((address_space(3))) void*)(buf + 1792), 16, 0, 0);
}

// Half-split FK compute, in place in buf (R11's proven layout, fi<14).
__device__ __forceinline__ void compute_tile(float* buf, int lane) {
    const int half = lane >> 5;      // 0: joints 0-10, 1: joints 11-21
    const int fi = lane & 31;        // frame index (valid < 14)
    const bool act = (fi < TILE_FRAMES);

    float* base = buf + fi * 132;
    const float* src = base + 66 * half;

    float L[11][9];
    if (act) {
#pragma unroll
        for (int i = 0; i < 11; ++i) local_rot(src + 6 * i, L[i]);
    }

    float e8[9], e9[9];
    if (act && half == 0) {
        float Rg[11][9];
#pragma unroll
        for (int k = 0; k < 9; ++k) Rg[0][k] = L[0][k];
        matmul3(Rg[1], Rg[0], L[1]);
        matmul3(Rg[2], Rg[0], L[2]);
        matmul3(Rg[3], Rg[0], L[3]);
        matmul3(Rg[4], Rg[1], L[4]);
        matmul3(Rg[5], Rg[2], L[5]);
        matmul3(Rg[6], Rg[3], L[6]);
        matmul3(Rg[7], Rg[4], L[7]);
        matmul3(Rg[8], Rg[5], L[8]);
        matmul3(Rg[9], Rg[6], L[9]);
        matmul3(Rg[10], Rg[7], L[10]);
#pragma unroll
        for (int i = 0; i < 11; ++i)
#pragma unroll
            for (int k = 0; k < 6; ++k) base[6 * i + k] = Rg[i][k];
#pragma unroll
        for (int k = 0; k < 9; ++k) { e8[k] = Rg[8][k]; e9[k] = Rg[9][k]; }
    }

#pragma unroll
    for (int k = 0; k < 9; ++k) {
        e8[k] = __shfl_xor(e8[k], 32, 64);
        e9[k] = __shfl_xor(e9[k], 32, 64);
    }

    if (act && half == 1) {
        float Rg[11][9];  // local idx i = joint 11+i
        matmul3(Rg[0], e8, L[0]);       // j11 <- j8
        matmul3(Rg[1], e9, L[1]);       // j12 <- j9
        matmul3(Rg[2], e9, L[2]);       // j13 <- j9
        matmul3(Rg[3], e9, L[3]);       // j14 <- j9
        matmul3(Rg[4], Rg[1], L[4]);    // j15 <- j12
        matmul3(Rg[5], Rg[2], L[5]);    // j16 <- j13
        matmul3(Rg[6], Rg[3], L[6]);    // j17 <- j14
        matmul3(Rg[7], Rg[5], L[7]);    // j18 <- j16
        matmul3(Rg[8], Rg[6], L[8]);    // j19 <- j17
        matmul3(Rg[9], Rg[7], L[9]);    // j20 <- j18
        matmul3(Rg[10], Rg[8], L[10]);  // j21 <- j19
#pragma unroll
        for (int i = 0; i < 11; ++i)
#pragma unroll
            for (int k = 0; k < 6; ++k) base[66 + 6 * i + k] = Rg[i][k];
    }
}

__global__ __launch_bounds__(TPB) void fk6d_kernel(const float* __restrict__ in,
                                                   float* __restrict__ out,
                                                   int NT, int G)
{
    __shared__ float lds[2][TILE_FLOATS];  // 14784 B -> 11 blocks/CU
    const int lane = threadIdx.x;

    int t = blockIdx.x;
    if (t < NT) stage_tile(in, t, lds[0], lane);

    int cur = 0;
    bool first = true;
    for (; t < NT; t += G) {
        // tile t's 8 loads done; up to 8 newer ops (t-1's stores) in flight
        if (first) {
            asm volatile("s_waitcnt vmcnt(0)" ::: "memory");
            first = false;
        } else {
            asm volatile("s_waitcnt vmcnt(8)" ::: "memory");
        }

        int nxt = t + G;
        if (nxt < NT) stage_tile(in, nxt, lds[cur ^ 1], lane);
        asm volatile("" ::: "memory");  // pin DMA issue before compute/stores

        compute_tile(lds[cur], lane);
        asm volatile("s_waitcnt lgkmcnt(0)" ::: "memory");  // LDS writes visible

        // 8 coalesced store instructions: 7 full float4 rounds + 14-lane tail
        float* gdst = out + (size_t)t * TILE_FLOATS;
        const float4* l4 = reinterpret_cast<const float4*>(lds[cur]);
        float4* o4 = reinterpret_cast<float4*>(gdst);
#pragma unroll
        for (int k = 0; k < 7; ++k) o4[k * 64 + lane] = l4[k * 64 + lane];
        if (lane < TILE_FRAMES) o4[448 + lane] = l4[448 + lane];

        cur ^= 1;
    }
}

// scalar tail (not taken: 100352 % 14 == 0)
__global__ void fk6d_tail(const float* __restrict__ in, float* __restrict__ out,
                          int n0, int N) {
    constexpr int PAR[22] = {0, 0, 0, 0, 1, 2, 3, 4, 5, 6, 7, 8, 9, 9, 9,
                             12, 13, 14, 16, 17, 18, 19};
    int n = n0 + blockIdx.x * blockDim.x + threadIdx.x;
    if (n >= N) return;
    const float* src = in + (size_t)n * 132;
    float* dst = out + (size_t)n * 132;
    float Rg[22][9];
#pragma unroll
    for (int j = 0; j < 22; ++j) {
        float Lr[9];
        local_rot(src + 6 * j, Lr);
        if (j == 0) {
#pragma unroll
            for (int k = 0; k < 9; ++k) Rg[0][k] = Lr[k];
        } else {
            matmul3(Rg[j], Rg[PAR[j]], Lr);
        }
#pragma unroll
        for (int k = 0; k < 6; ++k) dst[6 * j + k] = Rg[j][k];
    }
}

extern "C" void kernel_launch(void* const* d_in, const int* in_sizes, int n_in,
                              void* d_out, int out_size, void* d_ws, size_t ws_size,
                              hipStream_t stream) {
    const float* in = (const float*)d_in[0];
    float* out = (float*)d_out;
    int N = in_sizes[0] / 132;        // 100352 frames
    int NT = N / TILE_FRAMES;         // 7168 full tiles
    int G = 2816;                     // 11 blocks/CU on 256 CUs, persistent
    if (G > NT) G = (NT > 0 ? NT : 1);
    if (NT > 0) fk6d_kernel<<<G, TPB, 0, stream>>>(in, out, NT, G);
    int rem = N - NT * TILE_FRAMES;
    if (rem > 0)
        fk6d_tail<<<(rem + 63) / 64, 64, 0, stream>>>(in, out, NT * TILE_FRAMES, N);
}

// Round 14
// 27.932 us; speedup vs baseline: 1.2174x; 1.2174x over previous
//
#include <hip/hip_runtime.h>

// FK over the SMPL joint tree — R11 structure at a 16-frame tile for the
// last big TLP step. Block = 64 threads = 1 wave = 16 frames; LDS = 8448 B
// -> 19 blocks/CU (vs R11's 11). 16 | 100352 -> 6272 blocks, no tail.
// Stage: 8 async 1024B global_load_lds dwordx4 chunks + one 256B chunk
// (lanes 0-15) — zero over-read. Compute: half-split, fi = lane&31 (<16),
// half h = lane>>5 (h=0: joints 0-10, h=1: joints 11-21); Gram-Schmidt
// lane-uniform over active lanes; Rg8/Rg9 handoff via __shfl_xor(.,32);
// exec-masked half-chains. Outputs overwrite input slots in LDS;
// coalesced b128 store (8 rounds + 16-lane tail).

#define TPB 64
#define TILE_FRAMES 16
#define TILE_FLOATS (TILE_FRAMES * 132)  // 2112 floats = 8448 B

__device__ __forceinline__ void local_rot(const float* s, float* L) {
    float a1x = s[0], a1y = s[1], a1z = s[2];
    float a2x = s[3], a2y = s[4], a2z = s[5];
    float n1 = sqrtf(a1x * a1x + a1y * a1y + a1z * a1z);
    float i1 = 1.0f / fmaxf(n1, 1e-12f);
    float b1x = a1x * i1, b1y = a1y * i1, b1z = a1z * i1;
    float dt = b1x * a2x + b1y * a2y + b1z * a2z;
    float cx = a2x - dt * b1x, cy = a2y - dt * b1y, cz = a2z - dt * b1z;
    float n2 = sqrtf(cx * cx + cy * cy + cz * cz);
    float i2 = 1.0f / fmaxf(n2, 1e-12f);
    L[0] = b1x; L[1] = b1y; L[2] = b1z;
    L[3] = cx * i2; L[4] = cy * i2; L[5] = cz * i2;
    L[6] = L[1] * L[5] - L[2] * L[4];
    L[7] = L[2] * L[3] - L[0] * L[5];
    L[8] = L[0] * L[4] - L[1] * L[3];
}

__device__ __forceinline__ void matmul3(float* G, const float* P, const float* L) {
#pragma unroll
    for (int r = 0; r < 3; ++r)
#pragma unroll
        for (int c = 0; c < 3; ++c)
            G[3 * r + c] = P[3 * r + 0] * L[0 + c] +
                           P[3 * r + 1] * L[3 + c] +
                           P[3 * r + 2] * L[6 + c];
}

__global__ __launch_bounds__(TPB) void fk6d_kernel(const float* __restrict__ in,
                                                   float* __restrict__ out)
{
    __shared__ float lds[TILE_FLOATS];  // 8448 B -> 19 blocks/CU
    const int lane = threadIdx.x;
    const int half = lane >> 5;      // 0: joints 0-10, 1: joints 11-21
    const int fi = lane & 31;        // frame index (valid < 16)
    const bool act = (fi < TILE_FRAMES);

    const float* gin = in + (size_t)blockIdx.x * TILE_FLOATS;
    float* gout = out + (size_t)blockIdx.x * TILE_FLOATS;

    // ---- async stage: 8 full 1024B chunks + 256B tail (lanes 0-15)
#pragma unroll
    for (int k = 0; k < 8; ++k)
        __builtin_amdgcn_global_load_lds(
            (const __attribute__((address_space(1))) void*)(gin + k * 256 + lane * 4),
            (__attribute__((address_space(3))) void*)(lds + k * 256), 16, 0, 0);
    if (lane < TILE_FRAMES)
        __builtin_amdgcn_global_load_lds(
            (const __attribute__((address_space(1))) void*)(gin + 2048 + lane * 4),
            (__attribute__((address_space(3))) void*)(lds + 2048), 16, 0, 0);
    __syncthreads();  // 1-wave block: vmcnt drain + cheap barrier

    float* base = lds + fi * 132;
    const float* src = base + 66 * half;

    // ---- phase 1 (uniform over active lanes): Gram-Schmidt, 11 joints
    float L[11][9];
    if (act) {
#pragma unroll
        for (int i = 0; i < 11; ++i) local_rot(src + 6 * i, L[i]);
    }

    // ---- phase 2 (half A): chain joints 0-10, write outs, extract Rg8/Rg9
    float e8[9], e9[9];
    if (act && half == 0) {
        float Rg[11][9];
#pragma unroll
        for (int k = 0; k < 9; ++k) Rg[0][k] = L[0][k];
        matmul3(Rg[1], Rg[0], L[1]);
        matmul3(Rg[2], Rg[0], L[2]);
        matmul3(Rg[3], Rg[0], L[3]);
        matmul3(Rg[4], Rg[1], L[4]);
        matmul3(Rg[5], Rg[2], L[5]);
        matmul3(Rg[6], Rg[3], L[6]);
        matmul3(Rg[7], Rg[4], L[7]);
        matmul3(Rg[8], Rg[5], L[8]);
        matmul3(Rg[9], Rg[6], L[9]);
        matmul3(Rg[10], Rg[7], L[10]);
#pragma unroll
        for (int i = 0; i < 11; ++i)
#pragma unroll
            for (int k = 0; k < 6; ++k) base[6 * i + k] = Rg[i][k];
#pragma unroll
        for (int k = 0; k < 9; ++k) { e8[k] = Rg[8][k]; e9[k] = Rg[9][k]; }
    }

    // ---- phase 3 (uniform): hand Rg8/Rg9 from lanes l to lanes l+32
#pragma unroll
    for (int k = 0; k < 9; ++k) {
        e8[k] = __shfl_xor(e8[k], 32, 64);
        e9[k] = __shfl_xor(e9[k], 32, 64);
    }

    // ---- phase 4 (half B): chain joints 11-21, write outs
    if (act && half == 1) {
        float Rg[11][9];  // local idx i = joint 11+i
        matmul3(Rg[0], e8, L[0]);       // j11 <- j8
        matmul3(Rg[1], e9, L[1]);       // j12 <- j9
        matmul3(Rg[2], e9, L[2]);       // j13 <- j9
        matmul3(Rg[3], e9, L[3]);       // j14 <- j9
        matmul3(Rg[4], Rg[1], L[4]);    // j15 <- j12
        matmul3(Rg[5], Rg[2], L[5]);    // j16 <- j13
        matmul3(Rg[6], Rg[3], L[6]);    // j17 <- j14
        matmul3(Rg[7], Rg[5], L[7]);    // j18 <- j16
        matmul3(Rg[8], Rg[6], L[8]);    // j19 <- j17
        matmul3(Rg[9], Rg[7], L[9]);    // j20 <- j18
        matmul3(Rg[10], Rg[8], L[10]);  // j21 <- j19
#pragma unroll
        for (int i = 0; i < 11; ++i)
#pragma unroll
            for (int k = 0; k < 6; ++k) base[66 + 6 * i + k] = Rg[i][k];
    }
    __syncthreads();  // 1-wave: LDS-write ordering before store reads

    // ---- coalesced store: 8 full float4 rounds + 16-lane tail
    const float4* l4 = reinterpret_cast<const float4*>(lds);
    float4* o4 = reinterpret_cast<float4*>(gout);
#pragma unroll
    for (int k = 0; k < 8; ++k) o4[k * 64 + lane] = l4[k * 64 + lane];
    if (lane < TILE_FRAMES) o4[512 + lane] = l4[512 + lane];
}

// scalar tail (not taken: 100352 % 16 == 0)
__global__ void fk6d_tail(const float* __restrict__ in, float* __restrict__ out,
                          int n0, int N) {
    constexpr int PAR[22] = {0, 0, 0, 0, 1, 2, 3, 4, 5, 6, 7, 8, 9, 9, 9,
                             12, 13, 14, 16, 17, 18, 19};
    int n = n0 + blockIdx.x * blockDim.x + threadIdx.x;
    if (n >= N) return;
    const float* src = in + (size_t)n * 132;
    float* dst = out + (size_t)n * 132;
    float Rg[22][9];
#pragma unroll
    for (int j = 0; j < 22; ++j) {
        float Lr[9];
        local_rot(src + 6 * j, Lr);
        if (j == 0) {
#pragma unroll
            for (int k = 0; k < 9; ++k) Rg[0][k] = Lr[k];
        } else {
            matmul3(Rg[j], Rg[PAR[j]], Lr);
        }
#pragma unroll
        for (int k = 0; k < 6; ++k) dst[6 * j + k] = Rg[j][k];
    }
}

extern "C" void kernel_launch(void* const* d_in, const int* in_sizes, int n_in,
                              void* d_out, int out_size, void* d_ws, size_t ws_size,
                              hipStream_t stream) {
    const float* in = (const float*)d_in[0];
    float* out = (float*)d_out;
    int N = in_sizes[0] / 132;        // 100352 frames
    int NT = N / TILE_FRAMES;         // 6272 full tiles
    if (NT > 0) fk6d_kernel<<<NT, TPB, 0, stream>>>(in, out);
    int rem = N - NT * TILE_FRAMES;
    if (rem > 0)
        fk6d_tail<<<(rem + 63) / 64, 64, 0, stream>>>(in, out, NT * TILE_FRAMES, N);
}

// Round 15
// 24.990 us; speedup vs baseline: 1.3607x; 1.1178x over previous
//
#include <hip/hip_runtime.h>

// FK over the SMPL joint tree — FINAL: revert to the best-measured variant
// (round 11). Block = 64 threads = 1 wave = 28 frames; LDS = 14784 B ->
// 11 blocks/CU. 28 | 100352 -> 3584 blocks, no tail launch.
// Stage: 14 async 1024B global_load_lds dwordx4 chunks + one 448B chunk
// (lanes 0-27) — zero over-read. Compute: lane l -> frame fi=l&31 (<28),
// half h=l>>5 (h=0: joints 0-10, h=1: joints 11-21). Gram-Schmidt is
// lane-uniform (11 joints/lane); Rg[8],Rg[9] hand off A->B via
// __shfl_xor(.,32); exec-masked half-chains. Outputs overwrite the frame's
// input slots in LDS; coalesced b128 store (14 rounds + 28-lane tail).
//
// Measured 24.93 us (R11). The TLP ladder (4->8->9->11 blocks/CU =
// 33.1->26.6->25.3->24.9 us) saturates here; pipelined (R12/R13) and
// higher-TLP/diluted (R14) variants all measured worse. ~4.2 TB/s
// effective vs 6.3 TB/s pure-copy — the gap is the LDS-transpose
// round-trip + per-tile drain inherent to this op's layout.

#define TPB 64
#define TILE_FRAMES 28
#define TILE_FLOATS (TILE_FRAMES * 132)  // 3696 floats = 14784 B

__device__ __forceinline__ void local_rot(const float* s, float* L) {
    float a1x = s[0], a1y = s[1], a1z = s[2];
    float a2x = s[3], a2y = s[4], a2z = s[5];
    float n1 = sqrtf(a1x * a1x + a1y * a1y + a1z * a1z);
    float i1 = 1.0f / fmaxf(n1, 1e-12f);
    float b1x = a1x * i1, b1y = a1y * i1, b1z = a1z * i1;
    float dt = b1x * a2x + b1y * a2y + b1z * a2z;
    float cx = a2x - dt * b1x, cy = a2y - dt * b1y, cz = a2z - dt * b1z;
    float n2 = sqrtf(cx * cx + cy * cy + cz * cz);
    float i2 = 1.0f / fmaxf(n2, 1e-12f);
    L[0] = b1x; L[1] = b1y; L[2] = b1z;
    L[3] = cx * i2; L[4] = cy * i2; L[5] = cz * i2;
    L[6] = L[1] * L[5] - L[2] * L[4];
    L[7] = L[2] * L[3] - L[0] * L[5];
    L[8] = L[0] * L[4] - L[1] * L[3];
}

__device__ __forceinline__ void matmul3(float* G, const float* P, const float* L) {
#pragma unroll
    for (int r = 0; r < 3; ++r)
#pragma unroll
        for (int c = 0; c < 3; ++c)
            G[3 * r + c] = P[3 * r + 0] * L[0 + c] +
                           P[3 * r + 1] * L[3 + c] +
                           P[3 * r + 2] * L[6 + c];
}

__global__ __launch_bounds__(TPB) void fk6d_kernel(const float* __restrict__ in,
                                                   float* __restrict__ out)
{
    __shared__ float lds[TILE_FLOATS];  // 14784 B -> 11 blocks/CU
    const int lane = threadIdx.x;
    const int half = lane >> 5;      // 0: joints 0-10, 1: joints 11-21
    const int fi = lane & 31;        // frame index (valid < 28)
    const bool act = (fi < TILE_FRAMES);

    const float* gin = in + (size_t)blockIdx.x * TILE_FLOATS;
    float* gout = out + (size_t)blockIdx.x * TILE_FLOATS;

    // ---- async stage: 14 full 1024B chunks + 448B tail (lanes 0-27)
#pragma unroll
    for (int k = 0; k < 14; ++k)
        __builtin_amdgcn_global_load_lds(
            (const __attribute__((address_space(1))) void*)(gin + k * 256 + lane * 4),
            (__attribute__((address_space(3))) void*)(lds + k * 256), 16, 0, 0);
    if (lane < TILE_FRAMES)
        __builtin_amdgcn_global_load_lds(
            (const __attribute__((address_space(1))) void*)(gin + 3584 + lane * 4),
            (__attribute__((address_space(3))) void*)(lds + 3584), 16, 0, 0);
    __syncthreads();  // 1-wave block: vmcnt drain + cheap barrier

    float* base = lds + fi * 132;
    const float* src = base + 66 * half;

    // ---- phase 1 (uniform): Gram-Schmidt for this lane's 11 joints
    float L[11][9];
    if (act) {
#pragma unroll
        for (int i = 0; i < 11; ++i) local_rot(src + 6 * i, L[i]);
    }

    // ---- phase 2 (half A): chain joints 0-10, write outs, extract Rg8/Rg9
    float e8[9], e9[9];
    if (act && half == 0) {
        float Rg[11][9];
#pragma unroll
        for (int k = 0; k < 9; ++k) Rg[0][k] = L[0][k];
        matmul3(Rg[1], Rg[0], L[1]);
        matmul3(Rg[2], Rg[0], L[2]);
        matmul3(Rg[3], Rg[0], L[3]);
        matmul3(Rg[4], Rg[1], L[4]);
        matmul3(Rg[5], Rg[2], L[5]);
        matmul3(Rg[6], Rg[3], L[6]);
        matmul3(Rg[7], Rg[4], L[7]);
        matmul3(Rg[8], Rg[5], L[8]);
        matmul3(Rg[9], Rg[6], L[9]);
        matmul3(Rg[10], Rg[7], L[10]);
#pragma unroll
        for (int i = 0; i < 11; ++i)
#pragma unroll
            for (int k = 0; k < 6; ++k) base[6 * i + k] = Rg[i][k];
#pragma unroll
        for (int k = 0; k < 9; ++k) { e8[k] = Rg[8][k]; e9[k] = Rg[9][k]; }
    }

    // ---- phase 3 (uniform): hand Rg8/Rg9 from lanes l to lanes l+32
#pragma unroll
    for (int k = 0; k < 9; ++k) {
        e8[k] = __shfl_xor(e8[k], 32, 64);
        e9[k] = __shfl_xor(e9[k], 32, 64);
    }

    // ---- phase 4 (half B): chain joints 11-21, write outs
    if (act && half == 1) {
        float Rg[11][9];  // local idx i = joint 11+i
        matmul3(Rg[0], e8, L[0]);       // j11 <- j8
        matmul3(Rg[1], e9, L[1]);       // j12 <- j9
        matmul3(Rg[2], e9, L[2]);       // j13 <- j9
        matmul3(Rg[3], e9, L[3]);       // j14 <- j9
        matmul3(Rg[4], Rg[1], L[4]);    // j15 <- j12
        matmul3(Rg[5], Rg[2], L[5]);    // j16 <- j13
        matmul3(Rg[6], Rg[3], L[6]);    // j17 <- j14
        matmul3(Rg[7], Rg[5], L[7]);    // j18 <- j16
        matmul3(Rg[8], Rg[6], L[8]);    // j19 <- j17
        matmul3(Rg[9], Rg[7], L[9]);    // j20 <- j18
        matmul3(Rg[10], Rg[8], L[10]);  // j21 <- j19
#pragma unroll
        for (int i = 0; i < 11; ++i)
#pragma unroll
            for (int k = 0; k < 6; ++k) base[66 + 6 * i + k] = Rg[i][k];
    }
    __syncthreads();  // 1-wave: LDS-write ordering before store reads

    // ---- coalesced store: 14 full float4 rounds + 28-lane tail
    const float4* l4 = reinterpret_cast<const float4*>(lds);
    float4* o4 = reinterpret_cast<float4*>(gout);
#pragma unroll
    for (int k = 0; k < 14; ++k) o4[k * 64 + lane] = l4[k * 64 + lane];
    if (lane < TILE_FRAMES) o4[896 + lane] = l4[896 + lane];
}

// scalar tail (not taken: 100352 % 28 == 0)
__global__ void fk6d_tail(const float* __restrict__ in, float* __restrict__ out,
                          int n0, int N) {
    constexpr int PAR[22] = {0, 0, 0, 0, 1, 2, 3, 4, 5, 6, 7, 8, 9, 9, 9,
                             12, 13, 14, 16, 17, 18, 19};
    int n = n0 + blockIdx.x * blockDim.x + threadIdx.x;
    if (n >= N) return;
    const float* src = in + (size_t)n * 132;
    float* dst = out + (size_t)n * 132;
    float Rg[22][9];
#pragma unroll
    for (int j = 0; j < 22; ++j) {
        float Lr[9];
        local_rot(src + 6 * j, Lr);
        if (j == 0) {
#pragma unroll
            for (int k = 0; k < 9; ++k) Rg[0][k] = Lr[k];
        } else {
            matmul3(Rg[j], Rg[PAR[j]], Lr);
        }
#pragma unroll
        for (int k = 0; k < 6; ++k) dst[6 * j + k] = Rg[j][k];
    }
}

extern "C" void kernel_launch(void* const* d_in, const int* in_sizes, int n_in,
                              void* d_out, int out_size, void* d_ws, size_t ws_size,
                              hipStream_t stream) {
    const float* in = (const float*)d_in[0];
    float* out = (float*)d_out;
    int N = in_sizes[0] / 132;        // 100352 frames
    int NT = N / TILE_FRAMES;         // 3584 full tiles
    if (NT > 0) fk6d_kernel<<<NT, TPB, 0, stream>>>(in, out);
    int rem = N - NT * TILE_FRAMES;
    if (rem > 0)
        fk6d_tail<<<(rem + 63) / 64, 64, 0, stream>>>(in, out, NT * TILE_FRAMES, N);
}